// Round 5
// baseline (648.782 us; speedup 1.0000x reference)
//
#include <hip/hip_runtime.h>
#include <hip/hip_bf16.h>

typedef unsigned short u16;
typedef __attribute__((ext_vector_type(8))) __bf16 bf16x8;   // 4 VGPRs: MFMA A/B frag
typedef __attribute__((ext_vector_type(4))) float f32x4;     // MFMA C/D frag
typedef __attribute__((ext_vector_type(4))) float f4v;
typedef __attribute__((ext_vector_type(8))) unsigned short u16x8;

__device__ __forceinline__ u16 f32_to_bf16(float f) {
  unsigned int u = __builtin_bit_cast(unsigned int, f);
  u += 0x7FFFu + ((u >> 16) & 1u);   // RNE (inputs finite)
  return (u16)(u >> 16);
}

// fast gelu: v * sigmoid(1.59577*(v + 0.044715 v^3))  [tanh-form, max abs err ~3e-3]
__device__ __forceinline__ float fast_gelu(float v) {
  float v2 = v * v;
  float t = v * fmaf(0.0713548162726f, v2, 1.5957691216057308f);
  float e = __expf(-t);
  float s = __builtin_amdgcn_rcpf(1.0f + e);
  return v * s;
}

// async 16B global -> LDS (global_load_lds_dwordx4). LDS dest: wave-uniform base + lane*16.
__device__ __forceinline__ void async_ld16(const void* gsrc, void* ldst) {
  __builtin_amdgcn_global_load_lds(
      (__attribute__((address_space(1))) void*)(unsigned long long)gsrc,
      (__attribute__((address_space(3))) void*)(unsigned long long)ldst,
      16, 0, 0);
}

// ---------------- fp32 -> bf16 elementwise (x) ----------------
__global__ void cvt_kernel(const float* __restrict__ in, u16* __restrict__ out, int n8) {
  int i = blockIdx.x * blockDim.x + threadIdx.x;
  if (i >= n8) return;
  const f4v* p = (const f4v*)(in + (size_t)i * 8);
  f4v a = p[0], b = p[1];
  u16x8 r;
  r[0] = f32_to_bf16(a[0]); r[1] = f32_to_bf16(a[1]);
  r[2] = f32_to_bf16(a[2]); r[3] = f32_to_bf16(a[3]);
  r[4] = f32_to_bf16(b[0]); r[5] = f32_to_bf16(b[1]);
  r[6] = f32_to_bf16(b[2]); r[7] = f32_to_bf16(b[3]);
  *(u16x8*)(out + (size_t)i * 8) = r;
}

// ------------- fp32 [E][R][C] -> bf16 [E][C][R] (weight transpose) -------------
// 64x64 tile, 256 threads. float4 global reads (16B/lane), u16x8 global writes (16B/lane).
// LDS tile stride 65 u16 (odd dword stride): write phase ~2-way, read phase 32 banks
// 2 lanes each -> conflict-free.
__global__ __launch_bounds__(256)
void tpose_cvt_kernel(const float* __restrict__ in, u16* __restrict__ out, int R, int C) {
  __shared__ u16 tile[64 * 65];
  const int e = blockIdx.z;
  const int c0 = blockIdx.x * 64, r0 = blockIdx.y * 64;
  const float* src = in + (size_t)e * R * C;
  u16* dst = out + (size_t)e * R * C;
  const int t = threadIdx.x;
#pragma unroll
  for (int i = 0; i < 4; ++i) {
    int idx = i * 256 + t;
    int row = idx >> 4, c4 = idx & 15;      // row 0..63, c4 chunk 0..15
    f4v v = *(const f4v*)&src[(size_t)(r0 + row) * C + (c0 + c4 * 4)];
    int base = row * 65 + c4 * 4;
    tile[base + 0] = f32_to_bf16(v[0]);
    tile[base + 1] = f32_to_bf16(v[1]);
    tile[base + 2] = f32_to_bf16(v[2]);
    tile[base + 3] = f32_to_bf16(v[3]);
  }
  __syncthreads();
#pragma unroll
  for (int i = 0; i < 2; ++i) {
    int idx = i * 256 + t;
    int c = idx >> 3, r8 = idx & 7;         // c 0..63, r8 0..7
    u16x8 v;
#pragma unroll
    for (int j = 0; j < 8; ++j) v[j] = tile[(r8 * 8 + j) * 65 + c];
    *(u16x8*)&dst[(size_t)(c0 + c) * R + r0 + r8 * 8] = v;
  }
}

// ---------------- grouped GEMM: out[m][n] = A[m][:] . Bt[e][n][:] ----------------
// 256x128 tile, 8 waves (4Mx2N, per-wave 64x64 -> acc 64 VGPR), BK=32, ring-3 LDS
// (lA 3x16KB + lB 3x8KB = 72 KB) -> TWO blocks/CU (4 waves/SIMD): co-resident
// blocks are mutually unsynchronized, so one block's LDS-read phase overlaps the
// other's MFMA phase (m114 mechanism). Counted vmcnt(3) per slice (stage 2 ahead,
// never drain to 0). XOR-swizzled chunks (0 bank conflicts, verified r2-r4).
// Balanced-contiguous XCD slot map (m204): with balanced tokens each XCD owns one
// expert -> B panel stays in that XCD's L2 (GEMM2 B-fetch 512->64 MB).
// Requires K % 64 == 0, Nn % 128 == 0, grid = (Nn/128)*72.
template <int FUSE>
__global__ __launch_bounds__(512, 4)
void grouped_gemm(const u16* __restrict__ A, const u16* __restrict__ Bt,
                  void* __restrict__ Out, const int* __restrict__ tokens,
                  int Mtot, int K, int Nn, int ntShift) {
  const int NT = 1 << ntShift;          // n-tiles (Nn/128)
  const int id = blockIdx.x;
  const int xcd = id & 7;               // HW round-robin XCD assignment
  const int within = id >> 3;
  const int idx = within >> ntShift;    // 0..8 (slot index within this XCD)
  const int ntile = within & (NT - 1);

  int nts[8]; int T = 0;
#pragma unroll
  for (int e = 0; e < 8; ++e) { nts[e] = (tokens[e] + 255) >> 8; T += nts[e]; }
  const int q = T >> 3, r = T & 7;
  const int share = q + (xcd < r ? 1 : 0);
  if (idx >= share) return;             // idle block (block-uniform, before barriers)
  const int slot = xcd * q + (xcd < r ? xcd : r) + idx;  // bijective, contiguous per XCD

  int row_start = 0, tiles_before = 0;
  int expert = -1, my_row0 = 0, rows_valid = 0;
#pragma unroll
  for (int e = 0; e < 8; ++e) {
    int nt = nts[e];
    if (expert < 0 && slot < tiles_before + nt) {
      expert = e;
      int mi = slot - tiles_before;
      my_row0 = row_start + mi * 256;
      rows_valid = tokens[e] - mi * 256;
      if (rows_valid > 256) rows_valid = 256;
    }
    tiles_before += nt;
    row_start += tokens[e];
  }

  const int n0 = ntile * 128;
  const u16* Bq = Bt + (size_t)expert * Nn * K + (size_t)n0 * K;

  __shared__ __align__(16) u16 lA[3][8192];  // 3 x 16KB ring (256 rows x 32 k)
  __shared__ __align__(16) u16 lB[3][4096];  // 3 x  8KB ring (128 rows x 32 k)

  const int tid = threadIdx.x;
  const int lane = tid & 63;
  const int wave = tid >> 6;
  const int wm = (wave >> 1) * 64;   // 4 M-quarters
  const int wn = (wave & 1) * 64;    // 2 N-halves
  const int fr = lane & 15;
  const int fq = lane >> 4;

  f32x4 acc[4][4];
#pragma unroll
  for (int i = 0; i < 4; ++i)
#pragma unroll
    for (int j = 0; j < 4; ++j) acc[i][j] = (f32x4){0.f, 0.f, 0.f, 0.f};

  // staging: thread tid fills slice slot (row = tid>>2 [+128 for A], chunk = tid&3)
  // at elem offset tid*8 [+4096]. Source chunk = stored chunk ^ ((row>>1)&3).
  const int sr = tid >> 2;
  const int swz = ((tid & 3) ^ ((sr >> 1) & 3)) * 8;
  int ga0 = my_row0 + sr;        if (ga0 > Mtot - 1) ga0 = Mtot - 1;  // clamp; store-masked
  int ga1 = my_row0 + 128 + sr;  if (ga1 > Mtot - 1) ga1 = Mtot - 1;
  const u16* pA0 = A + (size_t)ga0 * K + swz;
  const u16* pA1 = A + (size_t)ga1 * K + swz;
  const u16* pB  = Bq + (size_t)sr * K + swz;   // BN=128 rows: sr covers 0..127

  // fragment read: chunk fq of row lives at swizzled chunk (fq ^ ((fr>>1)&3));
  // (row>>1)&3 == (fr>>1)&3 since wm, wn, m*16, n*16 are all 0 mod 8.
  const int cswz = (fq ^ ((fr >> 1) & 3)) * 8;
  const int aoff0 = (wm + fr) * 32 + cswz;
  const int boff0 = (wn + fr) * 32 + cswz;

  const int nslices = K >> 5;

  // prologue: stage slices 0,1 (3 loads each: A-half0, A-half1, B)
  async_ld16(pA0, &lA[0][tid * 8]);
  async_ld16(pA1, &lA[0][4096 + tid * 8]);
  async_ld16(pB,  &lB[0][tid * 8]);
  async_ld16(pA0 + 32, &lA[1][tid * 8]);
  async_ld16(pA1 + 32, &lA[1][4096 + tid * 8]);
  async_ld16(pB  + 32, &lB[1][tid * 8]);

  int b = 0, sb = 2;
  for (int sl = 0; sl < nslices; ++sl) {
    // tail: re-issue current slice into the dead buffer -> vmcnt accounting uniform
    const int sk = (sl + 2 < nslices ? sl + 2 : sl) * 32;

    // outstanding: slice sl (3) + sl+1 (3); wait to 3 completes slice sl.
    asm volatile("s_waitcnt vmcnt(3)" ::: "memory");
    __builtin_amdgcn_s_barrier();   // publish slice sl to all waves; buf sb is dead
    asm volatile("" ::: "memory");

    // stage slice sl+2 into buf sb = (sl+2)%3 (HBM latency hides under 2 slices)
    async_ld16(pA0 + sk, &lA[sb][tid * 8]);
    async_ld16(pA1 + sk, &lA[sb][4096 + tid * 8]);
    async_ld16(pB  + sk, &lB[sb][tid * 8]);

    bf16x8 aF[4], bF[4];
#pragma unroll
    for (int n = 0; n < 4; ++n) bF[n] = *(const bf16x8*)&lB[b][boff0 + n * 512];
#pragma unroll
    for (int m = 0; m < 4; ++m) aF[m] = *(const bf16x8*)&lA[b][aoff0 + m * 512];

    __builtin_amdgcn_s_setprio(1);
#pragma unroll
    for (int m = 0; m < 4; ++m)
#pragma unroll
      for (int n = 0; n < 4; ++n)
        acc[m][n] = __builtin_amdgcn_mfma_f32_16x16x32_bf16(aF[m], bF[n], acc[m][n], 0, 0, 0);
    __builtin_amdgcn_s_setprio(0);

    b = (b == 2) ? 0 : b + 1;
    sb = (sb == 2) ? 0 : sb + 1;
  }

  // epilogue. C/D layout: col = lane&15, row = (lane>>4)*4 + reg  [m89-verified]
  if (FUSE) {
    u16* Op = (u16*)Out;
#pragma unroll
    for (int m = 0; m < 4; ++m) {
#pragma unroll
      for (int r2 = 0; r2 < 4; ++r2) {
        int lrow = wm + m * 16 + fq * 4 + r2;
        if (lrow < rows_valid) {
          size_t base = (size_t)(my_row0 + lrow) * Nn + (size_t)(n0 + wn + fr);
#pragma unroll
          for (int n = 0; n < 4; ++n)
            Op[base + n * 16] = f32_to_bf16(fast_gelu(acc[m][n][r2]));
        }
      }
    }
  } else {
    float* Op = (float*)Out;
#pragma unroll
    for (int m = 0; m < 4; ++m) {
#pragma unroll
      for (int r2 = 0; r2 < 4; ++r2) {
        int lrow = wm + m * 16 + fq * 4 + r2;
        if (lrow < rows_valid) {
          size_t base = (size_t)(my_row0 + lrow) * Nn + (size_t)(n0 + wn + fr);
#pragma unroll
          for (int n = 0; n < 4; ++n) Op[base + n * 16] = acc[m][n][r2];
        }
      }
    }
  }
}

extern "C" void kernel_launch(void* const* d_in, const int* in_sizes, int n_in,
                              void* d_out, int out_size, void* d_ws, size_t ws_size,
                              hipStream_t stream) {
  (void)in_sizes; (void)n_in; (void)out_size; (void)ws_size;
  const float* x  = (const float*)d_in[0];   // [N][H]
  const float* w1 = (const float*)d_in[1];   // [E][H][F]
  const float* w2 = (const float*)d_in[2];   // [E][F][H]
  const int* tokens = (const int*)d_in[3];   // [E]

  const int N = 16384, H = 1024, F = 4096, E = 8;

  // ws layout (bf16): x 32MB | w1^T 64MB | w2^T 64MB | intermediate 128MB  (~302 MB)
  u16* x_bf  = (u16*)d_ws;
  u16* w1t   = x_bf + (size_t)N * H;       // [E][F][H]
  u16* w2t   = w1t + (size_t)E * F * H;    // [E][H][F]
  u16* inter = w2t + (size_t)E * H * F;    // [N][F]

  cvt_kernel<<<dim3((N * H / 8 + 255) / 256), dim3(256), 0, stream>>>(x, x_bf, N * H / 8);
  tpose_cvt_kernel<<<dim3(F / 64, H / 64, E), dim3(256), 0, stream>>>(w1, w1t, H, F);
  tpose_cvt_kernel<<<dim3(H / 64, F / 64, E), dim3(256), 0, stream>>>(w2, w2t, F, H);

  // grid = (Nn/128) * 72 slots (9 per XCD; balanced-contiguous mapping in-kernel)
  // GEMM1: [N][H] x [H][F] -> gelu -> bf16 inter [N][F].  NT=32 -> 2304 blocks.
  grouped_gemm<1><<<dim3((F / 128) * 72), dim3(512), 0, stream>>>(
      x_bf, w1t, inter, tokens, N, H, F, 5);
  // GEMM2: [N][F] x [F][H] -> f32 out [N][H].  NT=8 -> 576 blocks.
  grouped_gemm<0><<<dim3((H / 128) * 72), dim3(512), 0, stream>>>(
      inter, w2t, (float*)d_out, tokens, N, F, H, 3);
}